// Round 2
// baseline (573.683 us; speedup 1.0000x reference)
//
#include <hip/hip_runtime.h>

// ---------------------------------------------------------------------------
// PrimitiveDecoder: 4-layer LSTM (NH=1024), T=101 steps, tiny head.
//
// Round-7 (= round-6 with compile-safe asm): single-barrier dataflow step.
//  - ONE __syncthreads per step: staging moved to iteration TAIL (poll t+1
//    after computing t) with double-buffered vh4[2][256].
//  - barrier2 replaced by LDS sentinel handoff: waves write hout[wv]
//    (volatile), wave 7 spin-reads the 8 dwords, resets to SENT, publishes
//    immediately -- global store starts at "all nonlins done", not "barrier
//    release + skew".
//  - 2-deep staggered pipelined poll as ONE self-contained asm block:
//    4 scalar dword loads per slot (individually nameable regs), vmcnt(4)
//    waits, per-lane completion via explicit exec-mask editing. Registers
//    are pinned inside the block => no deferred-wait register hazard.
//    Sampling period ~RT/2 instead of RT.
//  - head: both 16B loads issued back-to-back in one asm block, single
//    vmcnt(0) => 1 fabric RT instead of 2 on wave-6's path.
//  - staging waves (0-3) never global-store; wave 7 sole publisher, its
//    store-ack drains lazily. __expf-based sigmoid/tanh.
// ---------------------------------------------------------------------------

#define TT    101
#define NBLK  256
#define NTH   512
#define NREP  8
#define SLAB_U32 512                               // 1024 f16 per replica
#define HB16_BYTES (4 * TT * NREP * SLAB_U32 * 4)  // 6,615,040 B
#define OUT_PROBS 6464
#define OUT_SAMP  6666
#define SENT 0xFFFFFFFFu

typedef _Float16 h2 __attribute__((ext_vector_type(2)));

__device__ __forceinline__ h2 mkh2(float a, float b) {
    h2 r; r.x = (_Float16)a; r.y = (_Float16)b; return r;
}
__device__ __forceinline__ unsigned pack2(float a, float b) {
    return __builtin_bit_cast(unsigned, mkh2(a, b));
}
__device__ __forceinline__ h2 as_h2(unsigned u) { return __builtin_bit_cast(h2, u); }

#if __has_builtin(__builtin_amdgcn_fdot2)
__device__ __forceinline__ float fdot2(h2 a, h2 b, float c) {
    return __builtin_amdgcn_fdot2(a, b, c, false);
}
#else
__device__ __forceinline__ float fdot2(h2 a, h2 b, float c) {
    return fmaf((float)a.x, (float)b.x, fmaf((float)a.y, (float)b.y, c));
}
#endif

__device__ __forceinline__ void store4_bypass(unsigned* p, unsigned v) {
    asm volatile("global_store_dword %0, %1, off sc0 sc1" :: "v"(p), "v"(v) : "memory");
}

// Two 16B cache-bypass loads issued back-to-back, ONE vmcnt(0): 1 RT not 2.
// Untied multi-reg OUTPUTS are supported (only tied ones are not).
__device__ __forceinline__ void load32_bypass2(const uint4* p0, const uint4* p1,
                                               uint4& r0, uint4& r1) {
    asm volatile("global_load_dwordx4 %0, %2, off sc0 sc1\n\t"
                 "global_load_dwordx4 %1, %3, off sc0 sc1\n\t"
                 "s_waitcnt vmcnt(0)"
                 : "=&v"(r0), "=&v"(r1) : "v"(p0), "v"(p1) : "memory");
}

// 2-deep staggered pipelined poll of one 16B chunk -> registers, entirely
// inside one asm block (registers pinned; no deferred-wait hazard).
//  * two slots A,B of 4 scalar dword loads each (offsets 0/4/8/12)
//  * vmcnt(4): my 4 older loads landed, 4 newer in flight (any stale
//    pre-existing VMEM ops are older still and get drained too -- safe)
//  * per-lane completion: valid-mask m via v_cmp chain, result copied under
//    exec=m, lane removed from exec; loop until execz; restore exec, drain.
__device__ __forceinline__ uint4 poll16_pipe(const uint4* p) {
    unsigned r0, r1, r2, r3, a0, a1, a2, a3, b0, b1, b2, b3;
    unsigned long long se, sm, st;
    asm volatile(
        "s_mov_b64 %12, exec\n\t"
        "global_load_dword %4, %15, off sc0 sc1\n\t"
        "global_load_dword %5, %15, off offset:4 sc0 sc1\n\t"
        "global_load_dword %6, %15, off offset:8 sc0 sc1\n\t"
        "global_load_dword %7, %15, off offset:12 sc0 sc1\n\t"
        "s_sleep 8\n\t"
        "global_load_dword %8, %15, off sc0 sc1\n\t"
        "global_load_dword %9, %15, off offset:4 sc0 sc1\n\t"
        "global_load_dword %10, %15, off offset:8 sc0 sc1\n\t"
        "global_load_dword %11, %15, off offset:12 sc0 sc1\n\t"
        "Lploop%=:\n\t"
        "s_waitcnt vmcnt(4)\n\t"                    // slot A landed
        "v_cmp_ne_u32 vcc, -1, %4\n\t"
        "s_mov_b64 %13, vcc\n\t"
        "v_cmp_ne_u32 vcc, -1, %5\n\t"
        "s_and_b64 %13, %13, vcc\n\t"
        "v_cmp_ne_u32 vcc, -1, %6\n\t"
        "s_and_b64 %13, %13, vcc\n\t"
        "v_cmp_ne_u32 vcc, -1, %7\n\t"
        "s_and_b64 %13, %13, vcc\n\t"               // m = lanes with valid A
        "s_mov_b64 %14, exec\n\t"
        "s_mov_b64 exec, %13\n\t"
        "v_mov_b32 %0, %4\n\t"
        "v_mov_b32 %1, %5\n\t"
        "v_mov_b32 %2, %6\n\t"
        "v_mov_b32 %3, %7\n\t"
        "s_mov_b64 exec, %14\n\t"
        "s_andn2_b64 exec, exec, %13\n\t"           // drop satisfied lanes
        "s_cbranch_execz Lpdone%=\n\t"
        "global_load_dword %4, %15, off sc0 sc1\n\t"
        "global_load_dword %5, %15, off offset:4 sc0 sc1\n\t"
        "global_load_dword %6, %15, off offset:8 sc0 sc1\n\t"
        "global_load_dword %7, %15, off offset:12 sc0 sc1\n\t"
        "s_waitcnt vmcnt(4)\n\t"                    // slot B landed
        "v_cmp_ne_u32 vcc, -1, %8\n\t"
        "s_mov_b64 %13, vcc\n\t"
        "v_cmp_ne_u32 vcc, -1, %9\n\t"
        "s_and_b64 %13, %13, vcc\n\t"
        "v_cmp_ne_u32 vcc, -1, %10\n\t"
        "s_and_b64 %13, %13, vcc\n\t"
        "v_cmp_ne_u32 vcc, -1, %11\n\t"
        "s_and_b64 %13, %13, vcc\n\t"
        "s_mov_b64 %14, exec\n\t"
        "s_mov_b64 exec, %13\n\t"
        "v_mov_b32 %0, %8\n\t"
        "v_mov_b32 %1, %9\n\t"
        "v_mov_b32 %2, %10\n\t"
        "v_mov_b32 %3, %11\n\t"
        "s_mov_b64 exec, %14\n\t"
        "s_andn2_b64 exec, exec, %13\n\t"
        "s_cbranch_execz Lpdone%=\n\t"
        "global_load_dword %8, %15, off sc0 sc1\n\t"
        "global_load_dword %9, %15, off offset:4 sc0 sc1\n\t"
        "global_load_dword %10, %15, off offset:8 sc0 sc1\n\t"
        "global_load_dword %11, %15, off offset:12 sc0 sc1\n\t"
        "s_branch Lploop%=\n\t"
        "Lpdone%=:\n\t"
        "s_mov_b64 exec, %12\n\t"
        "s_waitcnt vmcnt(0)"                        // drain dangling loads
        : "=&v"(r0), "=&v"(r1), "=&v"(r2), "=&v"(r3),
          "=&v"(a0), "=&v"(a1), "=&v"(a2), "=&v"(a3),
          "=&v"(b0), "=&v"(b1), "=&v"(b2), "=&v"(b3),
          "=&s"(se), "=&s"(sm), "=&s"(st)
        : "v"(p)
        : "vcc", "scc", "memory");
    return make_uint4(r0, r1, r2, r3);
}

// rocPRIM-style full-wave (64) sum via DPP; total broadcast via readlane(63).
__device__ __forceinline__ float wave_sum(float x) {
    int v;
    v = __builtin_amdgcn_update_dpp(0, __builtin_bit_cast(int, x), 0x111, 0xf, 0xf, false);
    x += __builtin_bit_cast(float, v);                                  // row_shr:1
    v = __builtin_amdgcn_update_dpp(0, __builtin_bit_cast(int, x), 0x112, 0xf, 0xf, false);
    x += __builtin_bit_cast(float, v);                                  // row_shr:2
    v = __builtin_amdgcn_update_dpp(0, __builtin_bit_cast(int, x), 0x114, 0xf, 0xe, false);
    x += __builtin_bit_cast(float, v);                                  // row_shr:4
    v = __builtin_amdgcn_update_dpp(0, __builtin_bit_cast(int, x), 0x118, 0xf, 0xc, false);
    x += __builtin_bit_cast(float, v);                                  // row_shr:8
    v = __builtin_amdgcn_update_dpp(0, __builtin_bit_cast(int, x), 0x142, 0xa, 0xf, false);
    x += __builtin_bit_cast(float, v);                                  // row_bcast:15
    v = __builtin_amdgcn_update_dpp(0, __builtin_bit_cast(int, x), 0x143, 0xc, 0xf, false);
    x += __builtin_bit_cast(float, v);                                  // row_bcast:31
    return __builtin_bit_cast(float, __builtin_amdgcn_readlane(__builtin_bit_cast(int, x), 63));
}

// fast transcendentals (v_exp_f32-based); error ~1e-6 << f16 h quantization.
__device__ __forceinline__ float sigm(float x)   { return 1.f / (1.f + __expf(-x)); }
__device__ __forceinline__ float tanh_f(float x) { return 1.f - 2.f / (1.f + __expf(x + x)); }

// ---------------------------------------------------------------------------
__global__ __launch_bounds__(NTH, 2) void lstm_kernel(
    const float* __restrict__ z,
    const float* __restrict__ Wih, const float* __restrict__ Whh,
    const float* __restrict__ bih, const float* __restrict__ bhh,
    const float* __restrict__ Ws,  const float* __restrict__ bs,
    const float* __restrict__ Wp,  const float* __restrict__ bp,
    unsigned* __restrict__ hb16, float* __restrict__ out)
{
    const int tid  = threadIdx.x;
    const int wv   = tid >> 6;
    const int lane = tid & 63;
    const int l    = blockIdx.x >> 6;          // layer / group
    const int gb   = blockIdx.x & 63;          // block-in-group
    const int uA   = (gb << 4) + (wv << 1);    // wave's first unit

    __shared__ __align__(16) uint4 vh4[2][256]; // dbuf: [part1 128 | part2 128]
    __shared__ unsigned hout[8];               // packed h pair per wave (SENT-gated)

    // ---- weights -> registers (fp32 -> f16), chunk-aligned layout --------
    h2 w[8][16];
    #pragma unroll
    for (int r = 0; r < 8; ++r) {
        const int u = uA + (r >> 2);
        const int g = r & 3;
        const size_t row = ((size_t)((l << 12) + (g << 10) + u)) << 10;
        const float4* pa = (const float4*)(Whh + row + (lane << 3));
        const float4* pb = (const float4*)(Whh + row + 512 + (lane << 3));
        const float4* pc = (const float4*)(Wih + row + (lane << 3));
        const float4* pd = (const float4*)(Wih + row + 512 + (lane << 3));
        float4 f;
        f = pa[0]; w[r][0]  = mkh2(f.x, f.y); w[r][1]  = mkh2(f.z, f.w);
        f = pa[1]; w[r][2]  = mkh2(f.x, f.y); w[r][3]  = mkh2(f.z, f.w);
        f = pb[0]; w[r][4]  = mkh2(f.x, f.y); w[r][5]  = mkh2(f.z, f.w);
        f = pb[1]; w[r][6]  = mkh2(f.x, f.y); w[r][7]  = mkh2(f.z, f.w);
        f = pc[0]; w[r][8]  = mkh2(f.x, f.y); w[r][9]  = mkh2(f.z, f.w);
        f = pc[1]; w[r][10] = mkh2(f.x, f.y); w[r][11] = mkh2(f.z, f.w);
        f = pd[0]; w[r][12] = mkh2(f.x, f.y); w[r][13] = mkh2(f.z, f.w);
        f = pd[1]; w[r][14] = mkh2(f.x, f.y); w[r][15] = mkh2(f.z, f.w);
    }

    float bA[4], bB[4];
    #pragma unroll
    for (int g = 0; g < 4; ++g) {
        const int iA = (l << 12) + (g << 10) + uA;
        bA[g] = bih[iA] + bhh[iA];
        bB[g] = bih[iA + 1] + bhh[iA + 1];
    }

    // ---- head role (wave 6) ----------------------------------------------
    const bool role_states = (l == 0 && wv == 6);
    const bool role_probs  = (l == 1 && gb == 0 && wv == 6);
    float hw0[16], hw1[16], hb0 = 0.f, hb1 = 0.f;
    if (role_states) {
        #pragma unroll
        for (int k = 0; k < 16; ++k) hw0[k] = Ws[(gb << 10) + (lane << 4) + k];
        hb0 = bs[gb];
    } else if (role_probs) {
        #pragma unroll
        for (int k = 0; k < 16; ++k) {
            hw0[k] = Wp[(lane << 4) + k];
            hw1[k] = Wp[1024 + (lane << 4) + k];
        }
        hb0 = bp[0]; hb1 = bp[1];
    }
    int th = 0;

    float cstA = 0.f, cstB = 0.f;

    // ---- preamble: stage t=0 into vh4[0]; init hout sentinels ------------
    if (tid < 8) hout[tid] = SENT;
    if (wv < 2) {                                  // part1: h_l(-1) = 0
        const int c = (wv << 6) + lane;
        vh4[0][c] = make_uint4(0, 0, 0, 0);
    } else if (wv < 4) {                           // part2: z (l==0) or h_{l-1}(0)
        const int c = ((wv - 2) << 6) + lane;
        if (l == 0) {
            const float4 f0 = *(const float4*)(z + (c << 3));
            const float4 f1 = *(const float4*)(z + (c << 3) + 4);
            vh4[0][128 + c] = make_uint4(pack2(f0.x, f0.y), pack2(f0.z, f0.w),
                                         pack2(f1.x, f1.y), pack2(f1.z, f1.w));
        } else {
            const int rep = (gb + wv) & (NREP - 1);
            const uint4* slab = (const uint4*)(hb16 + (size_t)(((l - 1) * TT) * NREP + rep) * SLAB_U32);
            vh4[0][128 + c] = poll16_pipe(slab + c);
        }
    }
    __syncthreads();

    #pragma unroll 1
    for (int t = 0; t < TT; ++t) {
        const bool full = (l > 0) || (t == 0);
        const int rb = t & 1;

        // ---- dot: 8 gate rows per wave, from vh4[rb] ----
        float acc[8] = {0.f, 0.f, 0.f, 0.f, 0.f, 0.f, 0.f, 0.f};
        {
            const uint4 A1 = vh4[rb][lane];
            const uint4 A2 = vh4[rb][64 + lane];
            const unsigned a8[8] = {A1.x, A1.y, A1.z, A1.w, A2.x, A2.y, A2.z, A2.w};
            #pragma unroll
            for (int k = 0; k < 8; ++k) {
                const h2 v2 = as_h2(a8[k]);
                #pragma unroll
                for (int r = 0; r < 8; ++r) acc[r] = fdot2(w[r][k], v2, acc[r]);
            }
            if (full) {
                const uint4 B1 = vh4[rb][128 + lane];
                const uint4 B2 = vh4[rb][192 + lane];
                const unsigned b8[8] = {B1.x, B1.y, B1.z, B1.w, B2.x, B2.y, B2.z, B2.w};
                #pragma unroll
                for (int k = 0; k < 8; ++k) {
                    const h2 v2 = as_h2(b8[k]);
                    #pragma unroll
                    for (int r = 0; r < 8; ++r) acc[r] = fdot2(w[r][8 + k], v2, acc[r]);
                }
            }
        }

        // ---- DPP reduce (VALU pipe) -> uniform gate sums ----
        float tot[8];
        #pragma unroll
        for (int r = 0; r < 8; ++r) tot[r] = wave_sum(acc[r]);

        // ---- uniform nonlinearity on all lanes ----
        cstA = fmaf(sigm(tot[1] + bA[1]), cstA, sigm(tot[0] + bA[0]) * tanh_f(tot[2] + bA[2]));
        cstB = fmaf(sigm(tot[5] + bB[1]), cstB, sigm(tot[4] + bB[0]) * tanh_f(tot[6] + bB[2]));
        const float hA = sigm(tot[3] + bA[3]) * tanh_f(cstA);
        const float hB = sigm(tot[7] + bB[3]) * tanh_f(cstB);
        if (lane == 0) ((volatile unsigned*)hout)[wv] = pack2(hA, hB);

        if (wv == 7) {
            // ---- publish: LDS sentinel handoff (no barrier), then ONE
            // 64-lane scatter store (8 replicas x 8 dwords). Ack drains lazily.
            volatile unsigned* vho = (volatile unsigned*)hout;
            unsigned v = vho[lane & 7];
            while (v == SENT) { v = vho[lane & 7]; }
            if (lane < 8) vho[lane] = SENT;        // reset for t+1 (ordered by barrier)
            unsigned* addr = hb16 + (size_t)(l * TT + t) * NREP * SLAB_U32
                           + (size_t)(lane >> 3) * SLAB_U32 + (gb << 3) + (lane & 7);
            store4_bypass(addr, v);
        } else if (wv < 2) {
            // ---- tail staging part1(t+1) = h_l(t), pipelined poll ----
            if (t + 1 < TT) {
                const int c = (wv << 6) + lane;
                const int rep = (gb + wv) & (NREP - 1);
                const uint4* slab = (const uint4*)(hb16 + (size_t)((l * TT + t) * NREP + rep) * SLAB_U32);
                vh4[rb ^ 1][c] = poll16_pipe(slab + c);
            }
        } else if (wv < 4) {
            // ---- tail staging part2(t+1) = h_{l-1}(t+1) ----
            if (t + 1 < TT && l > 0) {
                const int c = ((wv - 2) << 6) + lane;
                const int rep = (gb + wv) & (NREP - 1);
                const uint4* slab = (const uint4*)(hb16 + (size_t)(((l - 1) * TT + (t + 1)) * NREP + rep) * SLAB_U32);
                vh4[rb ^ 1][128 + c] = poll16_pipe(slab + c);
            }
        } else if ((role_states || role_probs) && th < TT && th <= t - 3) {
            // ---- head: non-blocking single-shot try at lag 3 (1 RT) ----
            const int hrep = (gb + th) & (NREP - 1);
            const uint4* slab3 = (const uint4*)(hb16 + (size_t)((3 * TT + th) * NREP + hrep) * SLAB_U32);
            uint4 r0, r1;
            load32_bypass2(slab3 + (lane << 1), slab3 + (lane << 1) + 1, r0, r1);
            const bool ok = !(r0.x == SENT || r0.y == SENT || r0.z == SENT || r0.w == SENT ||
                              r1.x == SENT || r1.y == SENT || r1.z == SENT || r1.w == SENT);
            if (__ballot(ok) == ~0ull) {
                const unsigned u8[8] = {r0.x, r0.y, r0.z, r0.w, r1.x, r1.y, r1.z, r1.w};
                if (role_states) {
                    float a = 0.f;
                    #pragma unroll
                    for (int j = 0; j < 8; ++j) {
                        const h2 p = as_h2(u8[j]);
                        a = fmaf(hw0[2 * j], (float)p.x, a);
                        a = fmaf(hw0[2 * j + 1], (float)p.y, a);
                    }
                    const float tots = wave_sum(a);
                    if (lane == 0) out[th * 64 + gb] = tots + hb0;
                } else {
                    float a0 = 0.f, a1 = 0.f;
                    #pragma unroll
                    for (int j = 0; j < 8; ++j) {
                        const h2 p = as_h2(u8[j]);
                        a0 = fmaf(hw0[2 * j], (float)p.x, a0); a0 = fmaf(hw0[2 * j + 1], (float)p.y, a0);
                        a1 = fmaf(hw1[2 * j], (float)p.x, a1); a1 = fmaf(hw1[2 * j + 1], (float)p.y, a1);
                    }
                    const float t0 = wave_sum(a0), t1 = wave_sum(a1);
                    if (lane == 0) {
                        float p0, p1;
                        if (th == TT - 1) { p0 = 0.f; p1 = 1.f; }
                        else {
                            const float l0 = t0 + hb0 + 1.0f;   // P_BIAS
                            const float l1 = t1 + hb1;
                            const float m  = fmaxf(l0, l1);
                            const float e0 = expf(l0 - m), e1 = expf(l1 - m);
                            const float inv = 1.f / (e0 + e1);
                            p0 = e0 * inv; p1 = e1 * inv;
                        }
                        out[OUT_PROBS + 2 * th]     = p0;
                        out[OUT_PROBS + 2 * th + 1] = p1;
                        out[OUT_SAMP + th] = (th == TT - 1) ? 1.0f : 0.0f;
                    }
                }
                ++th;
            }
        }
        __syncthreads();                           // the ONLY barrier per step
    }

    // ---- head drain (blocking) ----
    if (role_states || role_probs) {
        while (th < TT) {
            const int hrep = (gb + th) & (NREP - 1);
            const uint4* slab3 = (const uint4*)(hb16 + (size_t)((3 * TT + th) * NREP + hrep) * SLAB_U32);
            uint4 r0, r1;
            for (;;) {
                load32_bypass2(slab3 + (lane << 1), slab3 + (lane << 1) + 1, r0, r1);
                if (!(r0.x == SENT || r0.y == SENT || r0.z == SENT || r0.w == SENT ||
                      r1.x == SENT || r1.y == SENT || r1.z == SENT || r1.w == SENT)) break;
                __builtin_amdgcn_s_sleep(1);
            }
            const unsigned u8[8] = {r0.x, r0.y, r0.z, r0.w, r1.x, r1.y, r1.z, r1.w};
            if (role_states) {
                float a = 0.f;
                #pragma unroll
                for (int j = 0; j < 8; ++j) {
                    const h2 p = as_h2(u8[j]);
                    a = fmaf(hw0[2 * j], (float)p.x, a);
                    a = fmaf(hw0[2 * j + 1], (float)p.y, a);
                }
                const float tots = wave_sum(a);
                if (lane == 0) out[th * 64 + gb] = tots + hb0;
            } else {
                float a0 = 0.f, a1 = 0.f;
                #pragma unroll
                for (int j = 0; j < 8; ++j) {
                    const h2 p = as_h2(u8[j]);
                    a0 = fmaf(hw0[2 * j], (float)p.x, a0); a0 = fmaf(hw0[2 * j + 1], (float)p.y, a0);
                    a1 = fmaf(hw1[2 * j], (float)p.x, a1); a1 = fmaf(hw1[2 * j + 1], (float)p.y, a1);
                }
                const float t0 = wave_sum(a0), t1 = wave_sum(a1);
                if (lane == 0) {
                    float p0, p1;
                    if (th == TT - 1) { p0 = 0.f; p1 = 1.f; }
                    else {
                        const float l0 = t0 + hb0 + 1.0f;
                        const float l1 = t1 + hb1;
                        const float m  = fmaxf(l0, l1);
                        const float e0 = expf(l0 - m), e1 = expf(l1 - m);
                        const float inv = 1.f / (e0 + e1);
                        p0 = e0 * inv; p1 = e1 * inv;
                    }
                    out[OUT_PROBS + 2 * th]     = p0;
                    out[OUT_PROBS + 2 * th + 1] = p1;
                    out[OUT_SAMP + th] = (th == TT - 1) ? 1.0f : 0.0f;
                }
            }
            ++th;
        }
    }
}

// ---------------------------------------------------------------------------
extern "C" void kernel_launch(void* const* d_in, const int* in_sizes, int n_in,
                              void* d_out, int out_size, void* d_ws, size_t ws_size,
                              hipStream_t stream)
{
    const float* z   = (const float*)d_in[0];
    const float* Wih = (const float*)d_in[1];
    const float* Whh = (const float*)d_in[2];
    const float* bih = (const float*)d_in[3];
    const float* bhh = (const float*)d_in[4];
    const float* Ws  = (const float*)d_in[5];
    const float* bs  = (const float*)d_in[6];
    const float* Wp  = (const float*)d_in[7];
    const float* bp  = (const float*)d_in[8];
    float* out = (float*)d_out;

    unsigned* hb16 = (unsigned*)d_ws;

    // sentinel-init replicas (ws is re-poisoned before every timed call)
    hipMemsetAsync(hb16, 0xFF, HB16_BYTES, stream);
    lstm_kernel<<<NBLK, NTH, 0, stream>>>(z, Wih, Whh, bih, bhh,
                                          Ws, bs, Wp, bp, hb16, out);
}